// Round 14
// baseline (344.812 us; speedup 1.0000x reference)
//
#include <hip/hip_runtime.h>
#include <hip/hip_bf16.h>

#define SEQ 2048
#define NB 8
#define DIM 1024

typedef __attribute__((ext_vector_type(4))) float f32x4;
typedef __attribute__((ext_vector_type(8))) short bf16x8;
typedef __attribute__((ext_vector_type(4))) unsigned short u16x4;

__device__ __forceinline__ unsigned short f2bf(float f) {
    __hip_bfloat16 h = __float2bfloat16(f);           // RNE
    return *reinterpret_cast<unsigned short*>(&h);
}
__device__ __forceinline__ float bf2f(unsigned short u) {
    union { unsigned u; float f; } x; x.u = ((unsigned)u) << 16;
    return x.f;
}
// tanh(x) = 1 - 2/(e^{2x}+1); exact at +-inf, ~1e-7 rel err (v_rcp_f32)
__device__ __forceinline__ float fast_tanh(float x) {
    float e = __expf(x + x);
    float r = __builtin_amdgcn_rcpf(e + 1.0f);
    return fmaf(-2.0f, r, 1.0f);
}

// ------------- weight convert: slabs [Kw1, Qw1, Kw2, Qw2] -------------
__global__ __launch_bounds__(256) void convert_w4(const float* __restrict__ kw1,
                                                  const float* __restrict__ kw2,
                                                  const float* __restrict__ qw1,
                                                  const float* __restrict__ qw2,
                                                  unsigned short* __restrict__ out) {
    int sel = blockIdx.y;   // 0:Kw1 1:Qw1 2:Kw2 3:Qw2
    const float* src = sel == 0 ? kw1 : (sel == 1 ? qw1 : (sel == 2 ? kw2 : qw2));
    int i = blockIdx.x * 256 + threadIdx.x;
    float4 v = reinterpret_cast<const float4*>(src)[i];
    u16x4 o = { f2bf(v.x), f2bf(v.y), f2bf(v.z), f2bf(v.w) };
    reinterpret_cast<u16x4*>(out + (size_t)sel * DIM * DIM)[i] = o;
}

// ---- fused: xb[b][s][d] AND xbT[b][d][s] from seq[s][b][d] in one read ----
__global__ __launch_bounds__(256) void make_xbxbT(const float* __restrict__ seq,
                                                  unsigned short* __restrict__ xb,
                                                  unsigned short* __restrict__ xbT) {
    __shared__ unsigned short tile[64][65];
    int s0 = blockIdx.x * 64, d0 = blockIdx.y * 64, b = blockIdx.z;
    int t = threadIdx.x;
    int dx = (t & 15) * 4, sy = t >> 4;
    #pragma unroll
    for (int i = 0; i < 4; ++i) {
        int s = s0 + sy + i * 16;
        float4 v = *reinterpret_cast<const float4*>(seq + ((size_t)s * NB + b) * DIM + d0 + dx);
        u16x4 o = { f2bf(v.x), f2bf(v.y), f2bf(v.z), f2bf(v.w) };
        tile[sy + i * 16][dx + 0] = o[0];
        tile[sy + i * 16][dx + 1] = o[1];
        tile[sy + i * 16][dx + 2] = o[2];
        tile[sy + i * 16][dx + 3] = o[3];
        *reinterpret_cast<u16x4*>(xb + ((size_t)b * SEQ + s) * DIM + d0 + dx) = o;
    }
    __syncthreads();
    int sx = (t & 15) * 4, dy = t >> 4;
    #pragma unroll
    for (int i = 0; i < 4; ++i) {
        int d = d0 + dy + i * 16;
        u16x4 o = { tile[sx + 0][dy + i * 16], tile[sx + 1][dy + i * 16],
                    tile[sx + 2][dy + i * 16], tile[sx + 3][dy + i * 16] };
        *reinterpret_cast<u16x4*>(xbT + ((size_t)b * DIM + d) * SEQ + s0 + sx) = o;
    }
}

// =====================  256x256 ring GEMM, 8 waves, front-loaded ds_reads  =====
// MODE 0: C bf16 = tanh(acc) (+sC*bz); if rowsum && bx==0 && bz==0, zero rowsum rows
// MODE 3: C bf16 = exp(acc*scale); per-row partial sums atomicAdd -> rowsum
// MODE 4: C f32  = acc / rowsum[bz*SEQ+row]   (+sC*bz)
// All 24 fragment ds_reads issue at tile top in pinned order
// [b01+a0-3 (12) | b23 (4) | a4-7 (8)]; phases drain lgkmcnt(12)/(8)/(0).
// Stage ring unchanged from r12: Ph0 A0(u+1), Ph1 A1(u+1), Ph2 B0(u+2),
// Ph3 B1(u+2)+vmcnt(4). WAR: B stages after Ph1's lgkm(8)+barrier (all B reads
// done); A(u+1) -> other buffer. vmcnt FIFO identical to r12.
__device__ __forceinline__ void gload16(const unsigned short* g, unsigned short* l) {
    __builtin_amdgcn_global_load_lds((const __attribute__((address_space(1))) void*)g,
                                     (__attribute__((address_space(3))) void*)l,
                                     16, 0, 0);
}

#define MFMA16(I0, J0)                                                                            \
    _Pragma("unroll")                                                                             \
    for (int ks = 0; ks < 2; ++ks)                                                                \
        _Pragma("unroll")                                                                         \
        for (int ii = 0; ii < 4; ++ii)                                                            \
            _Pragma("unroll")                                                                     \
            for (int jj = 0; jj < 2; ++jj)                                                        \
                acc[I0 + ii][J0 + jj] = __builtin_amdgcn_mfma_f32_16x16x32_bf16(                   \
                    a[I0 + ii][ks], b[J0 + jj][ks], acc[I0 + ii][J0 + jj], 0, 0, 0);

template<int MODE>
__global__ __launch_bounds__(512, 2) void gemm256(
    const unsigned short* __restrict__ A, size_t sA, int lda,
    const unsigned short* __restrict__ B, size_t sB, int ldb,
    void* __restrict__ Cv, size_t sC, int ldc,
    int K, float scale, float* __restrict__ rowsum)
{
    __shared__ unsigned short AsF[2 * 2 * 8192];
    __shared__ unsigned short BsF[2 * 2 * 8192];

    // ---- T1: bijective XCD swizzle (all grids divisible by 8) ----
    const int gx = gridDim.x, gy = gridDim.y;
    const int nwg = gx * gy * gridDim.z;
    const int fid = blockIdx.x + gx * (blockIdx.y + gy * blockIdx.z);
    const int cpx = nwg >> 3;
    const int sw = (fid & 7) * cpx + (fid >> 3);
    const int bx = sw % gx;
    const int rem = sw / gx;
    const int by = rem % gy;
    const int bz = rem / gy;

    const unsigned short* Ab = A + sA * bz;
    const unsigned short* Bb = B + sB * bz;
    const int m0 = by * 256;
    const int n0 = bx * 256;

    const int t_ = threadIdx.x;
    const int lane = t_ & 63;
    const int w = t_ >> 6;
    const int wm = w >> 2;
    const int wn = w & 3;

    // MODE 0 helper duty: zero rowsum for the following QK dispatch.
    if (MODE == 0 && rowsum != nullptr && bx == 0 && bz == 0 && t_ < 256)
        rowsum[m0 + t_] = 0.0f;

    const int l3 = lane >> 3;
    const int g7 = lane & 7;
    const size_t h128a = (size_t)128 * lda, r8a = (size_t)8 * lda;
    const size_t h128b = (size_t)128 * ldb, r8b = (size_t)8 * ldb;
    // pre-swizzled source: LDS[row][g] holds global[row][g ^ (row&7)]
    const unsigned short* gA = Ab + (size_t)(m0 + w * 16 + l3) * lda + ((g7 ^ l3) << 3);
    const unsigned short* gB = Bb + (size_t)(n0 + w * 16 + l3) * ldb + ((g7 ^ l3) << 3);

    const int fr = lane & 15;
    const int hi4 = lane >> 4;
    const int off0 = fr * 64 + (((hi4) ^ g7) << 3);
    const int off1 = fr * 64 + (((4 + hi4) ^ g7) << 3);
    const int bno = (wn & 1) * 4096;
    const int wlds = w * 1024;

    f32x4 acc[8][4] = {};
    const int NT = K >> 6;

    // ---- prologue: tile0 {A0,A1,B0,B1} -> buf0; tile1 {B0,B1} -> buf1 ----
    gload16(gA, AsF + wlds);                     gload16(gA + r8a, AsF + wlds + 512);
    gload16(gA + h128a, AsF + 8192 + wlds);      gload16(gA + h128a + r8a, AsF + 8192 + wlds + 512);
    gload16(gB, BsF + wlds);                     gload16(gB + r8b, BsF + wlds + 512);
    gload16(gB + h128b, BsF + 8192 + wlds);      gload16(gB + h128b + r8b, BsF + 8192 + wlds + 512);
    {
        const unsigned short* gb1 = gB + 64;
        gload16(gb1, BsF + 16384 + wlds);                gload16(gb1 + r8b, BsF + 16384 + wlds + 512);
        gload16(gb1 + h128b, BsF + 16384 + 8192 + wlds); gload16(gb1 + h128b + r8b, BsF + 16384 + 8192 + wlds + 512);
    }
    asm volatile("s_waitcnt vmcnt(4)" ::: "memory");
    __builtin_amdgcn_s_barrier();

    const unsigned short* gA1 = gA + 64;
    const unsigned short* gB2 = gB + 128;

    for (int u = 0; u < NT; ++u) {
        const int bu = (u & 1) * 16384;
        const int bn = 16384 - bu;
        const unsigned short* pA = AsF + bu + wm * 8192;
        const unsigned short* pB = BsF + bu + (wn >> 1) * 8192 + bno;
        const bool pfA = (u + 1 < NT);
        const bool pfB = (u + 2 < NT);
        bf16x8 a[8][2], b[4][2];

        // ==== tile-top: issue ALL fragment reads, order pinned by sched_barrier ====
        // group 1 (12): b01 + a0-3   -> Ph0 needs these
        #pragma unroll
        for (int j = 0; j < 2; ++j) {
            b[j][0] = *(const bf16x8*)&pB[j * 1024 + off0];
            b[j][1] = *(const bf16x8*)&pB[j * 1024 + off1];
        }
        #pragma unroll
        for (int i = 0; i < 4; ++i) {
            a[i][0] = *(const bf16x8*)&pA[i * 1024 + off0];
            a[i][1] = *(const bf16x8*)&pA[i * 1024 + off1];
        }
        __builtin_amdgcn_sched_barrier(0);
        // group 2 (4): b23           -> Ph1 adds these
        #pragma unroll
        for (int j = 2; j < 4; ++j) {
            b[j][0] = *(const bf16x8*)&pB[j * 1024 + off0];
            b[j][1] = *(const bf16x8*)&pB[j * 1024 + off1];
        }
        __builtin_amdgcn_sched_barrier(0);
        // group 3 (8): a4-7          -> Ph2 adds these
        #pragma unroll
        for (int i = 4; i < 8; ++i) {
            a[i][0] = *(const bf16x8*)&pA[i * 1024 + off0];
            a[i][1] = *(const bf16x8*)&pA[i * 1024 + off1];
        }

        // ---------- Ph0: stage A0(u+1) ; lgkm(12) ; MFMA a0-3 x b01 ----------
        if (pfA) { gload16(gA1, AsF + bn + wlds); gload16(gA1 + r8a, AsF + bn + wlds + 512); }
        __builtin_amdgcn_s_barrier();
        asm volatile("s_waitcnt lgkmcnt(12)" ::: "memory");
        __builtin_amdgcn_sched_barrier(0);
        __builtin_amdgcn_s_setprio(1);
        MFMA16(0, 0)
        __builtin_amdgcn_s_setprio(0);
        __builtin_amdgcn_s_barrier();

        // ---------- Ph1: stage A1(u+1) ; lgkm(8) ; MFMA a0-3 x b23 ----------
        if (pfA) { gload16(gA1 + h128a, AsF + bn + 8192 + wlds); gload16(gA1 + h128a + r8a, AsF + bn + 8192 + wlds + 512); }
        __builtin_amdgcn_s_barrier();
        asm volatile("s_waitcnt lgkmcnt(8)" ::: "memory");
        __builtin_amdgcn_sched_barrier(0);
        __builtin_amdgcn_s_setprio(1);
        MFMA16(0, 2)
        __builtin_amdgcn_s_setprio(0);
        __builtin_amdgcn_s_barrier();

        // ---------- Ph2: stage B0(u+2) ; lgkm(0) ; MFMA a4-7 x b01 ----------
        if (pfB) { gload16(gB2, BsF + bu + wlds); gload16(gB2 + r8b, BsF + bu + wlds + 512); }
        __builtin_amdgcn_s_barrier();
        asm volatile("s_waitcnt lgkmcnt(0)" ::: "memory");
        __builtin_amdgcn_sched_barrier(0);
        __builtin_amdgcn_s_setprio(1);
        MFMA16(4, 0)
        __builtin_amdgcn_s_setprio(0);
        __builtin_amdgcn_s_barrier();

        // ---------- Ph3: stage B1(u+2) ; vmcnt ; MFMA a4-7 x b23 ----------
        if (pfB) {
            gload16(gB2 + h128b, BsF + bu + 8192 + wlds);
            gload16(gB2 + h128b + r8b, BsF + bu + 8192 + wlds + 512);
            asm volatile("s_waitcnt vmcnt(4)" ::: "memory");
        } else {
            asm volatile("s_waitcnt vmcnt(0)" ::: "memory");
        }
        __builtin_amdgcn_s_barrier();
        __builtin_amdgcn_sched_barrier(0);
        __builtin_amdgcn_s_setprio(1);
        MFMA16(4, 2)
        __builtin_amdgcn_s_setprio(0);
        __builtin_amdgcn_s_barrier();

        gA1 += 64; gB2 += 64;
    }

    // ---- epilogue: C/D layout col=lane&15, row=(lane>>4)*4+r ----
    if (MODE == 0) {
        unsigned short* C = reinterpret_cast<unsigned short*>(Cv) + sC * bz;
        #pragma unroll
        for (int mi = 0; mi < 8; ++mi)
            #pragma unroll
            for (int ni = 0; ni < 4; ++ni)
                #pragma unroll
                for (int r = 0; r < 4; ++r) {
                    int row = m0 + wm * 128 + mi * 16 + hi4 * 4 + r;
                    int col = n0 + wn * 64 + ni * 16 + fr;
                    C[(size_t)row * ldc + col] = f2bf(fast_tanh(acc[mi][ni][r]));
                }
    } else if (MODE == 3) {
        unsigned short* C = reinterpret_cast<unsigned short*>(Cv) + sC * bz;
        #pragma unroll
        for (int mi = 0; mi < 8; ++mi)
            #pragma unroll
            for (int r = 0; r < 4; ++r) {
                int row = m0 + wm * 128 + mi * 16 + hi4 * 4 + r;
                float ps = 0.f;
                #pragma unroll
                for (int ni = 0; ni < 4; ++ni) {
                    unsigned short h = f2bf(__expf(acc[mi][ni][r] * scale));
                    C[(size_t)row * ldc + (n0 + wn * 64 + ni * 16 + fr)] = h;
                    ps += bf2f(h);
                }
                ps += __shfl_xor(ps, 1, 64);
                ps += __shfl_xor(ps, 2, 64);
                ps += __shfl_xor(ps, 4, 64);
                ps += __shfl_xor(ps, 8, 64);
                if (fr == 0) atomicAdd(&rowsum[(size_t)bz * SEQ + row], ps);
            }
    } else {
        float* C = reinterpret_cast<float*>(Cv) + sC * bz;
        #pragma unroll
        for (int mi = 0; mi < 8; ++mi)
            #pragma unroll
            for (int r = 0; r < 4; ++r) {
                int row = m0 + wm * 128 + mi * 16 + hi4 * 4 + r;
                float invs = 1.0f / rowsum[(size_t)bz * SEQ + row];
                #pragma unroll
                for (int ni = 0; ni < 4; ++ni) {
                    int col = n0 + wn * 64 + ni * 16 + fr;
                    C[(size_t)row * ldc + col] = acc[mi][ni][r] * invs;
                }
            }
    }
}

// ---------------- launch ----------------
extern "C" void kernel_launch(void* const* d_in, const int* in_sizes, int n_in,
                              void* d_out, int out_size, void* d_ws, size_t ws_size,
                              hipStream_t stream) {
    const float* seq  = (const float*)d_in[0];
    const float* Kw1f = (const float*)d_in[1];
    const float* Kw2f = (const float*)d_in[2];
    const float* Qw1f = (const float*)d_in[3];
    const float* Qw2f = (const float*)d_in[4];
    float* out = (float*)d_out;

    // Workspace (168 MiB):
    //   [0,8)    W slabs [Kw1,Qw1,Kw2,Qw2]; rowsum aliases [0,64KB) after MLP1
    //   [8,40)   xbT                        (live until PV)
    //   [40,104) hKQ [16384 x 2048]         (dead after MLP2; P aliases it)
    //   [104,168) kq: keys [104,136), qrs [136,168)
    //   xb aliases [104,136)                (dead before keys written in MLP2)
    char* ws = (char*)d_ws;
    const size_t MB = 1024 * 1024;
    unsigned short* W    = (unsigned short*)(ws);
    unsigned short* Wkq1 = W;                                  // slabs 0,1 = [Kw1;Qw1]
    unsigned short* Wk2s = W + 2 * (size_t)DIM * DIM;          // slabs 2,3 = Wk2,Wq2
    unsigned short* xbT  = (unsigned short*)(ws + 8 * MB);
    unsigned short* hKQ  = (unsigned short*)(ws + 40 * MB);
    unsigned short* kq   = (unsigned short*)(ws + 104 * MB);   // keys then qrs
    unsigned short* xb   = kq;                                 // aliases keys region
    unsigned short* P    = hKQ;                                // aliases hKQ
    float* rowsum        = (float*)(ws);                       // 64 KB, Kw1 dead by MLP2

    convert_w4<<<dim3(DIM * DIM / 4 / 256, 4), 256, 0, stream>>>(Kw1f, Kw2f, Qw1f, Qw2f, W);
    make_xbxbT<<<dim3(SEQ / 64, DIM / 64, NB), 256, 0, stream>>>(seq, xb, xbT);

    // MLP1 merged: hKQ[16384,2048] = tanh(xb @ [Kw1;Qw1]^T)
    gemm256<0><<<dim3(2 * DIM / 256, (NB * SEQ) / 256, 1), 512, 0, stream>>>(
        xb, 0, DIM, Wkq1, 0, DIM, hKQ, 0, 2 * DIM, DIM, 1.0f, nullptr);

    // MLP2 batched z=2: keys = tanh(hK @ Wk2^T), qrs = tanh(hQ @ Wq2^T); zeroes rowsum
    gemm256<0><<<dim3(DIM / 256, (NB * SEQ) / 256, 2), 512, 0, stream>>>(
        hKQ, (size_t)DIM, 2 * DIM, Wk2s, (size_t)DIM * DIM, DIM,
        kq, (size_t)NB * SEQ * DIM, DIM, DIM, 1.0f, rowsum);

    // QK: P[b,s,t] = exp(keys[b,s,:].qrs[b,t,:]/32), rowsum accumulated
    gemm256<3><<<dim3(SEQ / 256, SEQ / 256, NB), 512, 0, stream>>>(
        kq, (size_t)SEQ * DIM, DIM, kq + (size_t)NB * SEQ * DIM, (size_t)SEQ * DIM, DIM,
        P, (size_t)SEQ * SEQ, SEQ, DIM, 0.03125f, rowsum);

    // PV: out[s,b,:] = (P[b,s,:] @ x[b]) / rowsum[b,s]
    gemm256<4><<<dim3(DIM / 256, SEQ / 256, NB), 512, 0, stream>>>(
        P, (size_t)SEQ * SEQ, SEQ, xbT, (size_t)DIM * SEQ, SEQ,
        out, (size_t)DIM, NB * DIM, SEQ, 1.0f, rowsum);
}

// Round 15
// 321.804 us; speedup vs baseline: 1.0715x; 1.0715x over previous
//
#include <hip/hip_runtime.h>
#include <hip/hip_bf16.h>

#define SEQ 2048
#define NB 8
#define DIM 1024

typedef __attribute__((ext_vector_type(4))) float f32x4;
typedef __attribute__((ext_vector_type(8))) short bf16x8;
typedef __attribute__((ext_vector_type(4))) unsigned short u16x4;

__device__ __forceinline__ unsigned short f2bf(float f) {
    __hip_bfloat16 h = __float2bfloat16(f);           // RNE
    return *reinterpret_cast<unsigned short*>(&h);
}
__device__ __forceinline__ float bf2f(unsigned short u) {
    union { unsigned u; float f; } x; x.u = ((unsigned)u) << 16;
    return x.f;
}
// tanh(x) = 1 - 2/(e^{2x}+1); exact at +-inf, ~1e-7 rel err (v_rcp_f32)
__device__ __forceinline__ float fast_tanh(float x) {
    float e = __expf(x + x);
    float r = __builtin_amdgcn_rcpf(e + 1.0f);
    return fmaf(-2.0f, r, 1.0f);
}

// ------------- weight convert: slabs [Kw1, Qw1, Kw2, Qw2] -------------
__global__ __launch_bounds__(256) void convert_w4(const float* __restrict__ kw1,
                                                  const float* __restrict__ kw2,
                                                  const float* __restrict__ qw1,
                                                  const float* __restrict__ qw2,
                                                  unsigned short* __restrict__ out) {
    int sel = blockIdx.y;   // 0:Kw1 1:Qw1 2:Kw2 3:Qw2
    const float* src = sel == 0 ? kw1 : (sel == 1 ? qw1 : (sel == 2 ? kw2 : qw2));
    int i = blockIdx.x * 256 + threadIdx.x;
    float4 v = reinterpret_cast<const float4*>(src)[i];
    u16x4 o = { f2bf(v.x), f2bf(v.y), f2bf(v.z), f2bf(v.w) };
    reinterpret_cast<u16x4*>(out + (size_t)sel * DIM * DIM)[i] = o;
}

// ---- fused: xb[b][s][d] AND xbT[b][d][s] from seq[s][b][d] in one read ----
__global__ __launch_bounds__(256) void make_xbxbT(const float* __restrict__ seq,
                                                  unsigned short* __restrict__ xb,
                                                  unsigned short* __restrict__ xbT) {
    __shared__ unsigned short tile[64][65];
    int s0 = blockIdx.x * 64, d0 = blockIdx.y * 64, b = blockIdx.z;
    int t = threadIdx.x;
    int dx = (t & 15) * 4, sy = t >> 4;
    #pragma unroll
    for (int i = 0; i < 4; ++i) {
        int s = s0 + sy + i * 16;
        float4 v = *reinterpret_cast<const float4*>(seq + ((size_t)s * NB + b) * DIM + d0 + dx);
        u16x4 o = { f2bf(v.x), f2bf(v.y), f2bf(v.z), f2bf(v.w) };
        tile[sy + i * 16][dx + 0] = o[0];
        tile[sy + i * 16][dx + 1] = o[1];
        tile[sy + i * 16][dx + 2] = o[2];
        tile[sy + i * 16][dx + 3] = o[3];
        *reinterpret_cast<u16x4*>(xb + ((size_t)b * SEQ + s) * DIM + d0 + dx) = o;
    }
    __syncthreads();
    int sx = (t & 15) * 4, dy = t >> 4;
    #pragma unroll
    for (int i = 0; i < 4; ++i) {
        int d = d0 + dy + i * 16;
        u16x4 o = { tile[sx + 0][dy + i * 16], tile[sx + 1][dy + i * 16],
                    tile[sx + 2][dy + i * 16], tile[sx + 3][dy + i * 16] };
        *reinterpret_cast<u16x4*>(xbT + ((size_t)b * DIM + d) * SEQ + s0 + sx) = o;
    }
}

// =====================  256x256 8-phase GEMM (r6 ring, 16x16x32)  =====
// MODE 0: C bf16 = tanh(acc) (+sC*bz); if rowsum && bx==0 && bz==0, zero rowsum rows
// MODE 3: C bf16 = exp(acc*scale); per-row partial sums atomicAdd -> rowsum
// MODE 4: C f32  = acc / rowsum[bz*SEQ+row]   (+sC*bz)
__device__ __forceinline__ void gload16(const unsigned short* g, unsigned short* l) {
    __builtin_amdgcn_global_load_lds((const __attribute__((address_space(1))) void*)g,
                                     (__attribute__((address_space(3))) void*)l,
                                     16, 0, 0);
}

#define MFMA16(I0, J0)                                                                            \
    _Pragma("unroll")                                                                             \
    for (int ks = 0; ks < 2; ++ks)                                                                \
        _Pragma("unroll")                                                                         \
        for (int ii = 0; ii < 4; ++ii)                                                            \
            _Pragma("unroll")                                                                     \
            for (int jj = 0; jj < 2; ++jj)                                                        \
                acc[I0 + ii][J0 + jj] = __builtin_amdgcn_mfma_f32_16x16x32_bf16(                   \
                    a[I0 + ii][ks], b[J0 + jj][ks], acc[I0 + ii][J0 + jj], 0, 0, 0);

template<int MODE>
__global__ __launch_bounds__(512, 2) void gemm256(
    const unsigned short* __restrict__ A, size_t sA, int lda,
    const unsigned short* __restrict__ B, size_t sB, int ldb,
    void* __restrict__ Cv, size_t sC, int ldc,
    int K, float scale, float* __restrict__ rowsum)
{
    __shared__ unsigned short AsF[2 * 2 * 8192];
    __shared__ unsigned short BsF[2 * 2 * 8192];

    // ---- T1: bijective XCD swizzle (all grids divisible by 8) ----
    const int gx = gridDim.x, gy = gridDim.y;
    const int nwg = gx * gy * gridDim.z;
    const int fid = blockIdx.x + gx * (blockIdx.y + gy * blockIdx.z);
    const int cpx = nwg >> 3;
    const int sw = (fid & 7) * cpx + (fid >> 3);
    const int bx = sw % gx;
    const int rem = sw / gx;
    const int by = rem % gy;
    const int bz = rem / gy;

    const unsigned short* Ab = A + sA * bz;
    const unsigned short* Bb = B + sB * bz;
    const int m0 = by * 256;
    const int n0 = bx * 256;

    const int t_ = threadIdx.x;
    const int lane = t_ & 63;
    const int w = t_ >> 6;
    const int wm = w >> 2;
    const int wn = w & 3;

    // MODE 0 helper duty: zero rowsum for the following QK dispatch.
    // Safe: rowsum aliases the Kw1 slab, dead during MLP2; disjoint from B reads.
    if (MODE == 0 && rowsum != nullptr && bx == 0 && bz == 0 && t_ < 256)
        rowsum[m0 + t_] = 0.0f;

    const int l3 = lane >> 3;
    const int g7 = lane & 7;
    const size_t h128a = (size_t)128 * lda, r8a = (size_t)8 * lda;
    const size_t h128b = (size_t)128 * ldb, r8b = (size_t)8 * ldb;
    // pre-swizzled source: LDS[row][g] holds global[row][g ^ (row&7)]
    const unsigned short* gA = Ab + (size_t)(m0 + w * 16 + l3) * lda + ((g7 ^ l3) << 3);
    const unsigned short* gB = Bb + (size_t)(n0 + w * 16 + l3) * ldb + ((g7 ^ l3) << 3);

    const int fr = lane & 15;
    const int hi4 = lane >> 4;
    const int off0 = fr * 64 + (((hi4) ^ g7) << 3);
    const int off1 = fr * 64 + (((4 + hi4) ^ g7) << 3);
    const int bno = (wn & 1) * 4096;
    const int wlds = w * 1024;

    f32x4 acc[8][4] = {};
    const int NT = K >> 6;

    // ---- prologue: tile0 {A0,A1,B0,B1} -> buf0; tile1 {B0,B1} -> buf1 ----
    gload16(gA, AsF + wlds);                     gload16(gA + r8a, AsF + wlds + 512);
    gload16(gA + h128a, AsF + 8192 + wlds);      gload16(gA + h128a + r8a, AsF + 8192 + wlds + 512);
    gload16(gB, BsF + wlds);                     gload16(gB + r8b, BsF + wlds + 512);
    gload16(gB + h128b, BsF + 8192 + wlds);      gload16(gB + h128b + r8b, BsF + 8192 + wlds + 512);
    {
        const unsigned short* gb1 = gB + 64;
        gload16(gb1, BsF + 16384 + wlds);                gload16(gb1 + r8b, BsF + 16384 + wlds + 512);
        gload16(gb1 + h128b, BsF + 16384 + 8192 + wlds); gload16(gb1 + h128b + r8b, BsF + 16384 + 8192 + wlds + 512);
    }
    asm volatile("s_waitcnt vmcnt(4)" ::: "memory");
    __builtin_amdgcn_s_barrier();

    const unsigned short* gA1 = gA + 64;
    const unsigned short* gB2 = gB + 128;

    for (int u = 0; u < NT; ++u) {
        const int bu = (u & 1) * 16384;
        const int bn = 16384 - bu;
        const unsigned short* pA = AsF + bu + wm * 8192;
        const unsigned short* pB = BsF + bu + (wn >> 1) * 8192 + bno;
        const bool pfA = (u + 1 < NT);
        const bool pfB = (u + 2 < NT);
        bf16x8 a[8][2], b[4][2];

        // ---------- Ph0: read a0-3 + b01 ; stage A0(u+1) ; MFMA q00 ----------
        #pragma unroll
        for (int i = 0; i < 4; ++i) {
            a[i][0] = *(const bf16x8*)&pA[i * 1024 + off0];
            a[i][1] = *(const bf16x8*)&pA[i * 1024 + off1];
        }
        #pragma unroll
        for (int j = 0; j < 2; ++j) {
            b[j][0] = *(const bf16x8*)&pB[j * 1024 + off0];
            b[j][1] = *(const bf16x8*)&pB[j * 1024 + off1];
        }
        if (pfA) { gload16(gA1, AsF + bn + wlds); gload16(gA1 + r8a, AsF + bn + wlds + 512); }
        asm volatile("s_waitcnt lgkmcnt(8)" ::: "memory");
        __builtin_amdgcn_s_barrier();
        asm volatile("s_waitcnt lgkmcnt(0)" ::: "memory");
        __builtin_amdgcn_sched_barrier(0);
        __builtin_amdgcn_s_setprio(1);
        MFMA16(0, 0)
        __builtin_amdgcn_s_setprio(0);
        __builtin_amdgcn_s_barrier();

        // ---------- Ph1: read b23 ; stage A1(u+1) ; MFMA q01 ----------
        #pragma unroll
        for (int j = 2; j < 4; ++j) {
            b[j][0] = *(const bf16x8*)&pB[j * 1024 + off0];
            b[j][1] = *(const bf16x8*)&pB[j * 1024 + off1];
        }
        if (pfA) { gload16(gA1 + h128a, AsF + bn + 8192 + wlds); gload16(gA1 + h128a + r8a, AsF + bn + 8192 + wlds + 512); }
        __builtin_amdgcn_s_barrier();
        asm volatile("s_waitcnt lgkmcnt(0)" ::: "memory");
        __builtin_amdgcn_sched_barrier(0);
        __builtin_amdgcn_s_setprio(1);
        MFMA16(0, 2)
        __builtin_amdgcn_s_setprio(0);
        __builtin_amdgcn_s_barrier();

        // ---------- Ph2: read a4-7 ; stage B0(u+2) ; MFMA q10 ----------
        #pragma unroll
        for (int i = 4; i < 8; ++i) {
            a[i][0] = *(const bf16x8*)&pA[i * 1024 + off0];
            a[i][1] = *(const bf16x8*)&pA[i * 1024 + off1];
        }
        if (pfB) { gload16(gB2, BsF + bu + wlds); gload16(gB2 + r8b, BsF + bu + wlds + 512); }
        __builtin_amdgcn_s_barrier();
        asm volatile("s_waitcnt lgkmcnt(0)" ::: "memory");
        __builtin_amdgcn_sched_barrier(0);
        __builtin_amdgcn_s_setprio(1);
        MFMA16(4, 0)
        __builtin_amdgcn_s_setprio(0);
        __builtin_amdgcn_s_barrier();

        // ---------- Ph3: stage B1(u+2) ; vmcnt ; MFMA q11 ----------
        if (pfB) {
            gload16(gB2 + h128b, BsF + bu + 8192 + wlds);
            gload16(gB2 + h128b + r8b, BsF + bu + 8192 + wlds + 512);
            asm volatile("s_waitcnt vmcnt(4)" ::: "memory");
        } else {
            asm volatile("s_waitcnt vmcnt(0)" ::: "memory");
        }
        __builtin_amdgcn_s_barrier();
        __builtin_amdgcn_sched_barrier(0);
        __builtin_amdgcn_s_setprio(1);
        MFMA16(4, 2)
        __builtin_amdgcn_s_setprio(0);
        __builtin_amdgcn_s_barrier();

        gA1 += 64; gB2 += 64;
    }

    // ---- epilogue: C/D layout col=lane&15, row=(lane>>4)*4+r ----
    if (MODE == 0) {
        unsigned short* C = reinterpret_cast<unsigned short*>(Cv) + sC * bz;
        #pragma unroll
        for (int mi = 0; mi < 8; ++mi)
            #pragma unroll
            for (int ni = 0; ni < 4; ++ni)
                #pragma unroll
                for (int r = 0; r < 4; ++r) {
                    int row = m0 + wm * 128 + mi * 16 + hi4 * 4 + r;
                    int col = n0 + wn * 64 + ni * 16 + fr;
                    C[(size_t)row * ldc + col] = f2bf(fast_tanh(acc[mi][ni][r]));
                }
    } else if (MODE == 3) {
        unsigned short* C = reinterpret_cast<unsigned short*>(Cv) + sC * bz;
        #pragma unroll
        for (int mi = 0; mi < 8; ++mi)
            #pragma unroll
            for (int r = 0; r < 4; ++r) {
                int row = m0 + wm * 128 + mi * 16 + hi4 * 4 + r;
                float ps = 0.f;
                #pragma unroll
                for (int ni = 0; ni < 4; ++ni) {
                    unsigned short h = f2bf(__expf(acc[mi][ni][r] * scale));
                    C[(size_t)row * ldc + (n0 + wn * 64 + ni * 16 + fr)] = h;
                    ps += bf2f(h);
                }
                ps += __shfl_xor(ps, 1, 64);
                ps += __shfl_xor(ps, 2, 64);
                ps += __shfl_xor(ps, 4, 64);
                ps += __shfl_xor(ps, 8, 64);
                if (fr == 0) atomicAdd(&rowsum[(size_t)bz * SEQ + row], ps);
            }
    } else {
        float* C = reinterpret_cast<float*>(Cv) + sC * bz;
        #pragma unroll
        for (int mi = 0; mi < 8; ++mi)
            #pragma unroll
            for (int r = 0; r < 4; ++r) {
                int row = m0 + wm * 128 + mi * 16 + hi4 * 4 + r;
                float invs = 1.0f / rowsum[(size_t)bz * SEQ + row];
                #pragma unroll
                for (int ni = 0; ni < 4; ++ni) {
                    int col = n0 + wn * 64 + ni * 16 + fr;
                    C[(size_t)row * ldc + col] = acc[mi][ni][r] * invs;
                }
            }
    }
}

// ---------------- launch ----------------
extern "C" void kernel_launch(void* const* d_in, const int* in_sizes, int n_in,
                              void* d_out, int out_size, void* d_ws, size_t ws_size,
                              hipStream_t stream) {
    const float* seq  = (const float*)d_in[0];
    const float* Kw1f = (const float*)d_in[1];
    const float* Kw2f = (const float*)d_in[2];
    const float* Qw1f = (const float*)d_in[3];
    const float* Qw2f = (const float*)d_in[4];
    float* out = (float*)d_out;

    // Workspace (168 MiB):
    //   [0,8)    W slabs [Kw1,Qw1,Kw2,Qw2]; rowsum aliases [0,64KB) after MLP1
    //   [8,40)   xbT                        (live until PV)
    //   [40,104) hKQ [16384 x 2048]         (dead after MLP2; P aliases it)
    //   [104,168) kq: keys [104,136), qrs [136,168)
    //   xb aliases [104,136)                (dead before keys written in MLP2)
    char* ws = (char*)d_ws;
    const size_t MB = 1024 * 1024;
    unsigned short* W    = (unsigned short*)(ws);
    unsigned short* Wkq1 = W;                                  // slabs 0,1 = [Kw1;Qw1]
    unsigned short* Wk2s = W + 2 * (size_t)DIM * DIM;          // slabs 2,3 = Wk2,Wq2
    unsigned short* xbT  = (unsigned short*)(ws + 8 * MB);
    unsigned short* hKQ  = (unsigned short*)(ws + 40 * MB);
    unsigned short* kq   = (unsigned short*)(ws + 104 * MB);   // keys then qrs
    unsigned short* xb   = kq;                                 // aliases keys region
    unsigned short* P    = hKQ;                                // aliases hKQ
    float* rowsum        = (float*)(ws);                       // 64 KB, Kw1 dead by MLP2

    convert_w4<<<dim3(DIM * DIM / 4 / 256, 4), 256, 0, stream>>>(Kw1f, Kw2f, Qw1f, Qw2f, W);
    make_xbxbT<<<dim3(SEQ / 64, DIM / 64, NB), 256, 0, stream>>>(seq, xb, xbT);

    // MLP1 merged: hKQ[16384,2048] = tanh(xb @ [Kw1;Qw1]^T)
    gemm256<0><<<dim3(2 * DIM / 256, (NB * SEQ) / 256, 1), 512, 0, stream>>>(
        xb, 0, DIM, Wkq1, 0, DIM, hKQ, 0, 2 * DIM, DIM, 1.0f, nullptr);

    // MLP2 batched z=2: keys = tanh(hK @ Wk2^T), qrs = tanh(hQ @ Wq2^T); zeroes rowsum
    gemm256<0><<<dim3(DIM / 256, (NB * SEQ) / 256, 2), 512, 0, stream>>>(
        hKQ, (size_t)DIM, 2 * DIM, Wk2s, (size_t)DIM * DIM, DIM,
        kq, (size_t)NB * SEQ * DIM, DIM, DIM, 1.0f, rowsum);

    // QK: P[b,s,t] = exp(keys[b,s,:].qrs[b,t,:]/32), rowsum accumulated
    gemm256<3><<<dim3(SEQ / 256, SEQ / 256, NB), 512, 0, stream>>>(
        kq, (size_t)SEQ * DIM, DIM, kq + (size_t)NB * SEQ * DIM, (size_t)SEQ * DIM, DIM,
        P, (size_t)SEQ * SEQ, SEQ, DIM, 0.03125f, rowsum);

    // PV: out[s,b,:] = (P[b,s,:] @ x[b]) / rowsum[b,s]
    gemm256<4><<<dim3(DIM / 256, SEQ / 256, NB), 512, 0, stream>>>(
        P, (size_t)SEQ * SEQ, SEQ, xbT, (size_t)DIM * SEQ, SEQ,
        out, (size_t)DIM, NB * DIM, SEQ, 1.0f, rowsum);
}